// Round 1
// baseline (9000.873 us; speedup 1.0000x reference)
//
#include <hip/hip_runtime.h>

#define HH 51
#define TT 256
#define NB 16          // batch elements per workgroup
#define NROW 13        // gate rows per thread (16 jg-groups * 13 = 208 >= 204)

// ---------------- activation helpers (fp32, safe-clamped) ----------------
__device__ __forceinline__ float sigm(float x) {
    return 1.0f / (1.0f + __expf(-x));
}
__device__ __forceinline__ float tanh_fast(float x) {
    x = fminf(15.0f, fmaxf(-15.0f, x));
    float e = __expf(2.0f * x);
    return (e - 1.0f) / (e + 1.0f);
}

// ---------------- weight repack (runs every launch; d_ws is re-poisoned) ----
// Layouts (all padded with zeros so the main loop is branch-free):
//  W1r[(m*13 + k4)*16 + jg] : float4 = W_hh1[j][4k4..4k4+3], j = jg + 16*m, k padded to 52
//  W2r[(m*26 + k4)*16 + jg] : float4; k4<13 -> W_ih2[j][..] (k padded to 52),
//                                     k4>=13 -> W_hh2[j][..] (k padded to 52)
//  wx[m*16+jg] = W_ih1[j];  bb1 = b_ih1+b_hh1;  bb2 = b_ih2+b_hh2
__global__ void lstm_prep(const float* __restrict__ Wih1, const float* __restrict__ Whh1,
                          const float* __restrict__ bih1, const float* __restrict__ bhh1,
                          const float* __restrict__ Wih2, const float* __restrict__ Whh2,
                          const float* __restrict__ bih2, const float* __restrict__ bhh2,
                          float4* __restrict__ W1r, float4* __restrict__ W2r,
                          float* __restrict__ wx, float* __restrict__ bb1,
                          float* __restrict__ bb2) {
    int tid = blockIdx.x * blockDim.x + threadIdx.x;
    int stride = gridDim.x * blockDim.x;

    for (int e = tid; e < 13 * 13 * 16; e += stride) {
        int jg = e & 15, q = e >> 4;
        int k4 = q % 13, m = q / 13;
        int j = jg + 16 * m;
        float t[4] = {0.f, 0.f, 0.f, 0.f};
        if (j < 4 * HH) {
            for (int c = 0; c < 4; c++) {
                int k = 4 * k4 + c;
                if (k < HH) t[c] = Whh1[j * HH + k];
            }
        }
        W1r[e] = make_float4(t[0], t[1], t[2], t[3]);
    }
    for (int e = tid; e < 13 * 26 * 16; e += stride) {
        int jg = e & 15, q = e >> 4;
        int k4 = q % 26, m = q / 26;
        int j = jg + 16 * m;
        float t[4] = {0.f, 0.f, 0.f, 0.f};
        if (j < 4 * HH) {
            for (int c = 0; c < 4; c++) {
                int kk = 4 * k4 + c;
                if (kk < 52) {               // W_ih2 half (k = kk)
                    if (kk < HH) t[c] = Wih2[j * HH + kk];
                } else {                     // W_hh2 half (k = kk-52)
                    int k = kk - 52;
                    if (k < HH) t[c] = Whh2[j * HH + k];
                }
            }
        }
        W2r[e] = make_float4(t[0], t[1], t[2], t[3]);
    }
    for (int e = tid; e < 208; e += stride) {
        int jg = e & 15, m = e >> 4;
        int j = jg + 16 * m;
        bool ok = (j < 4 * HH);
        wx[e]  = ok ? Wih1[j] : 0.f;
        bb1[e] = ok ? (bih1[j] + bhh1[j]) : 0.f;
        bb2[e] = ok ? (bih2[j] + bhh2[j]) : 0.f;
    }
}

// ---------------- persistent LSTM kernel: 1 WG = 16 batch elements -------
__launch_bounds__(256, 1)
__global__ void lstm_main(const float* __restrict__ input,
                          const float4* __restrict__ W1r, const float4* __restrict__ W2r,
                          const float* __restrict__ wx_g, const float* __restrict__ bb1_g,
                          const float* __restrict__ bb2_g,
                          const float* __restrict__ Wlin, const float* __restrict__ blin,
                          float* __restrict__ out) {
    // h layout [b][52] (row stride 52 -> 2-way bank alias = free, 16B aligned rows)
    // c/gates layout [row][16] -> lanes hit consecutive banks
    __shared__ __align__(16) float h1[NB * 52];
    __shared__ __align__(16) float h2[NB * 52];
    __shared__ float c1[HH * NB];
    __shared__ float c2[HH * NB];
    __shared__ float gates[208 * NB];
    __shared__ float wl[52];

    const int tid = threadIdx.x;
    const int b  = tid & 15;     // batch sub-index
    const int jg = tid >> 4;     // gate-row group [0,16)
    const int b0 = blockIdx.x * NB;

    for (int i = tid; i < NB * 52; i += 256) { h1[i] = 0.f; h2[i] = 0.f; }
    for (int i = tid; i < HH * NB; i += 256) { c1[i] = 0.f; c2[i] = 0.f; }
    if (tid < 52) wl[tid] = (tid < HH) ? Wlin[tid] : 0.f;

    float wx[NROW], B1[NROW], B2[NROW];
#pragma unroll
    for (int m = 0; m < NROW; m++) {
        wx[m] = wx_g[m * 16 + jg];
        B1[m] = bb1_g[m * 16 + jg];
        B2[m] = bb2_g[m * 16 + jg];
    }
    const float bl = blin[0];
    const float* xrow = input + (size_t)(b0 + b) * TT;

    __syncthreads();

    for (int t = 0; t < TT; t++) {
        // ---------------- cell1 gates: j = jg + 16m, over k in h1 ----------
        float acc[NROW];
        {
            float xs = xrow[t];
#pragma unroll
            for (int m = 0; m < NROW; m++) acc[m] = fmaf(xs, wx[m], B1[m]);
        }
#pragma unroll 2
        for (int k4 = 0; k4 < 13; k4++) {
            float4 hv = *(const float4*)&h1[b * 52 + 4 * k4];
#pragma unroll
            for (int m = 0; m < NROW; m++) {
                float4 w = W1r[(m * 13 + k4) * 16 + jg];
                acc[m] = fmaf(w.x, hv.x, fmaf(w.y, hv.y, fmaf(w.z, hv.z, fmaf(w.w, hv.w, acc[m]))));
            }
        }
#pragma unroll
        for (int m = 0; m < NROW; m++) gates[(jg + 16 * m) * 16 + b] = acc[m];
        __syncthreads();

        // ---------------- cell1 update ------------------------------------
        for (int r = tid; r < NB * HH; r += 256) {
            int u = r >> 4, bb = r & 15;
            float ii = gates[u * 16 + bb];
            float ff = gates[(HH + u) * 16 + bb];
            float gg = gates[(2 * HH + u) * 16 + bb];
            float oo = gates[(3 * HH + u) * 16 + bb];
            float c = c1[u * 16 + bb];
            float cn = sigm(ff) * c + sigm(ii) * tanh_fast(gg);
            c1[u * 16 + bb] = cn;
            h1[bb * 52 + u] = sigm(oo) * tanh_fast(cn);
        }
        __syncthreads();

        // ---------------- cell2 gates: K = [h1 | h2] -----------------------
#pragma unroll
        for (int m = 0; m < NROW; m++) acc[m] = B2[m];
#pragma unroll 2
        for (int k4 = 0; k4 < 13; k4++) {
            float4 hv = *(const float4*)&h1[b * 52 + 4 * k4];
#pragma unroll
            for (int m = 0; m < NROW; m++) {
                float4 w = W2r[(m * 26 + k4) * 16 + jg];
                acc[m] = fmaf(w.x, hv.x, fmaf(w.y, hv.y, fmaf(w.z, hv.z, fmaf(w.w, hv.w, acc[m]))));
            }
        }
#pragma unroll 2
        for (int k4 = 0; k4 < 13; k4++) {
            float4 hv = *(const float4*)&h2[b * 52 + 4 * k4];
#pragma unroll
            for (int m = 0; m < NROW; m++) {
                float4 w = W2r[(m * 26 + 13 + k4) * 16 + jg];
                acc[m] = fmaf(w.x, hv.x, fmaf(w.y, hv.y, fmaf(w.z, hv.z, fmaf(w.w, hv.w, acc[m]))));
            }
        }
#pragma unroll
        for (int m = 0; m < NROW; m++) gates[(jg + 16 * m) * 16 + b] = acc[m];
        __syncthreads();

        // ---------------- cell2 update ------------------------------------
        for (int r = tid; r < NB * HH; r += 256) {
            int u = r >> 4, bb = r & 15;
            float ii = gates[u * 16 + bb];
            float ff = gates[(HH + u) * 16 + bb];
            float gg = gates[(2 * HH + u) * 16 + bb];
            float oo = gates[(3 * HH + u) * 16 + bb];
            float c = c2[u * 16 + bb];
            float cn = sigm(ff) * c + sigm(ii) * tanh_fast(gg);
            c2[u * 16 + bb] = cn;
            h2[bb * 52 + u] = sigm(oo) * tanh_fast(cn);
        }
        __syncthreads();

        // ---------------- head: out[b][t] = W_lin . h2 + b_lin -------------
        if (tid < NB) {
            float a = bl;
#pragma unroll
            for (int u = 0; u < HH; u++) a = fmaf(wl[u], h2[tid * 52 + u], a);
            out[(size_t)(b0 + tid) * TT + t] = a;
        }
        // no barrier needed: next gate1 touches only h1/gates; gates were
        // consumed before the update2 barrier, h2 is read only by head here.
    }
}

extern "C" void kernel_launch(void* const* d_in, const int* in_sizes, int n_in,
                              void* d_out, int out_size, void* d_ws, size_t ws_size,
                              hipStream_t stream) {
    const float* input = (const float*)d_in[0];
    const float* Wih1  = (const float*)d_in[1];
    const float* Whh1  = (const float*)d_in[2];
    const float* bih1  = (const float*)d_in[3];
    const float* bhh1  = (const float*)d_in[4];
    const float* Wih2  = (const float*)d_in[5];
    const float* Whh2  = (const float*)d_in[6];
    const float* bih2  = (const float*)d_in[7];
    const float* bhh2  = (const float*)d_in[8];
    const float* Wlin  = (const float*)d_in[9];
    const float* blin  = (const float*)d_in[10];

    float* ws = (float*)d_ws;
    float4* W1r = (float4*)ws;                  // 13*13*16 float4 = 10816 floats
    float4* W2r = (float4*)(ws + 10816);        // 13*26*16 float4 = 21632 floats
    float* wx  = ws + 10816 + 21632;            // 208
    float* bb1 = wx + 208;                      // 208
    float* bb2 = bb1 + 208;                     // 208

    int B = in_sizes[0] / TT;                   // 4096

    lstm_prep<<<64, 256, 0, stream>>>(Wih1, Whh1, bih1, bhh1, Wih2, Whh2, bih2, bhh2,
                                      W1r, W2r, wx, bb1, bb2);
    lstm_main<<<B / NB, 256, 0, stream>>>(input, W1r, W2r, wx, bb1, bb2, Wlin, blin,
                                          (float*)d_out);
}